// Round 19
// baseline (87.277 us; speedup 1.0000x reference)
//
#include <hip/hip_runtime.h>
#include <hip/hip_bf16.h>
#include <math.h>

// ---------------------------------------------------------------------------
// GaussianState: out(b) = Re logsumexp( lo(b,0), log(prod s)+lo(b,1) )
//   lo(b,h) = log Pf(W) + 63*ln2 - i*pi + lt(h);  lt = -sum(v^2)/8
// W: 128x128 complex skew, interleaved order; rank-2 Parlett-Reid, static 2x2
// pivots, deferred log. Round 19: STRIDED col ownership (wave w owns cols
// {w+16j}) -> cols retire uniformly across waves (max work = avg work; the
// barrier-gated step shrinks 8->0 cols over k). Pivot col held in registers
// (cK, extracted once per outer K via uniform ladder; j-loop is j>K) so all
// acc indices stay static. Pair cols staged as float2 halves by 2 waves.
// 1024 threads (4 waves/SIMD); rows q=t&63 + {0,64}.
// ---------------------------------------------------------------------------

#define PI_D  3.14159265358979323846264338328
#define LN2_D 0.69314718055994530941723212146

typedef float f32x2 __attribute__((ext_vector_type(2)));

__device__ __forceinline__ int sniff_mode(const void* x) {
    const unsigned int* u = (const unsigned int*)x;
    unsigned int lo = u[0], hi = u[1];
    if ((hi == 0x3FF00000u || hi == 0xBFF00000u) && lo == 0u) return 1;       // f64
    unsigned short a = (unsigned short)(lo & 0xFFFFu);
    unsigned short b = (unsigned short)(lo >> 16);
    if ((a == 0x3F80u || a == 0xBF80u) && (b == 0x3F80u || b == 0xBF80u)) return 2; // bf16
    return 0;                                                                  // f32
}

__device__ __forceinline__ double ld_in(const void* p, int idx, int mode) {
    if (mode == 1) return ((const double*)p)[idx];
    if (mode == 2) {
        unsigned int w = ((unsigned int)((const unsigned short*)p)[idx]) << 16;
        return (double)__uint_as_float(w);
    }
    return (double)((const float*)p)[idx];
}

// G(p,q) = -H[p][q]/2 from upper-tri storage of H (f32)
__device__ __forceinline__ float Gq(const float* Hu, int p, int q) {
    if (p == q) return 0.0f;
    int i = (p < q) ? p : q;
    int j = (p < q) ? q : p;
    float g = -0.5f * Hu[(i * (255 - i)) / 2 + (j - i - 1)];
    return (p < q) ? g : -g;
}

// W'(rn,cn) in interleaved order: even index -> old top q=n>>1, odd -> bottom.
__device__ __forceinline__ void Wq(const float* Hu, const float* tsg,
                                   int rn, int cn, float& re, float& im) {
    int A = rn >> 1, B = cn >> 1;
    if ((cn & 1) == 0) {
        if ((rn & 1) == 0) {
            re = 0.5f * (-Gq(Hu, 2*A, 2*B)   + Gq(Hu, 2*A+1, 2*B+1));
            im = 0.5f * (-Gq(Hu, 2*A, 2*B+1) - Gq(Hu, 2*A+1, 2*B));
        } else {
            int pA = (A + 1) & 63; float tA = tsg[A];
            float Fre = 0.5f * ( tA * Gq(Hu, 2*B, 2*A+1) + Gq(Hu, 2*B+1, 2*pA) );
            float Fim = 0.5f * ( -Gq(Hu, 2*B, 2*pA) + tA * Gq(Hu, 2*B+1, 2*A+1) );
            float Mim = 0.5f * ((B == A ? tA : 0.0f) - (B == pA ? 1.0f : 0.0f));
            re = Fre; im = Mim + Fim;
        }
    } else {
        if ((rn & 1) == 0) {
            int pB = (B + 1) & 63; float tB = tsg[B];
            float Fre = 0.5f * ( tB * Gq(Hu, 2*A, 2*B+1) + Gq(Hu, 2*A+1, 2*pB) );
            float Fim = 0.5f * ( -Gq(Hu, 2*A, 2*pB) + tB * Gq(Hu, 2*A+1, 2*B+1) );
            float Mim = 0.5f * ((A == B ? tB : 0.0f) - (A == pB ? 1.0f : 0.0f));
            re = -Fre; im = -Mim - Fim;
        } else {
            int pA = (A + 1) & 63, pB = (B + 1) & 63;
            float tA = tsg[A], tB = tsg[B];
            re = 0.5f * ( -tA * tB * Gq(Hu, 2*A+1, 2*B+1) + Gq(Hu, 2*pA, 2*pB) );
            im = 0.5f * (  tA * Gq(Hu, 2*A+1, 2*pB) + tB * Gq(Hu, 2*pA, 2*B+1) );
        }
    }
}

// packed complex update: a += z_beta*c1 - z_gamma*c2 (c1=cv.xy, c2=cv.zw)
__device__ __forceinline__ f32x2 upd8(f32x2 a, float br, float bi,
                                      float gr, float gi, float4 cv) {
    f32x2 c1 = (f32x2){cv.x, cv.y}, c2 = (f32x2){cv.z, cv.w};
    a = __builtin_elementwise_fma((f32x2){ br,  br}, c1,    a);
    a = __builtin_elementwise_fma((f32x2){-bi,  bi}, c1.yx, a);
    a = __builtin_elementwise_fma((f32x2){-gr, -gr}, c2,    a);
    a = __builtin_elementwise_fma((f32x2){ gi, -gi}, c2.yx, a);
    return a;
}

// --- per-(sample,ham) Pfaffian via 2x2-pivot block elimination -------------
// grid 256 = (b,h); 1024 threads: wave w=t>>6 -> cols {w+16j}, rows q=t&63+{0,64}
extern "C" __global__ void __launch_bounds__(1024)
GaussianState_24318104830346_kernel(const void* xin, const void* h1,
                                    const void* h2, double* lows) {
    const int t   = threadIdx.x;
    const int bid = blockIdx.x;
    const int b = bid & 127, h = bid >> 7;
    const int w    = t >> 6;                  // wave id (uniform)
    const int q    = t & 63;                  // row base / lane

    __shared__ float  tsg[64];
    __shared__ float4 xbuf[2][136];           // XI16-padded staged col pairs
    __shared__ double red[16];
    __shared__ float  Hu[8128];

    const int mode = sniff_mode(xin);
    const void* raw = h ? h2 : h1;

    // stage upper-tri H + accumulate sum(v^2) for lt
    double ss = 0.0;
    for (int f = t; f < 8128; f += 1024) {
        double v = ld_in(raw, f, mode);
        Hu[f] = (float)v;
        ss += v * v;
    }
#pragma unroll
    for (int off = 32; off >= 1; off >>= 1) ss += __shfl_xor(ss, off, 64);
    if (q == 0) red[w] = ss;

    if (t < 64) {
        float sA = (float)ld_in(xin, b * 64 + t, mode);
        float sB = (float)ld_in(xin, b * 64 + ((t + 1) & 63), mode);
        float tt = sA * sB;
        if (t == 63) tt = -tt;
        tsg[t] = tt;
    }
    __syncthreads();

    // build W' fragment: 2 strata x 8 strided cols {w+16j}
    f32x2 acc[2][8];
#pragma unroll
    for (int s = 0; s < 2; ++s)
#pragma unroll
        for (int j = 0; j < 8; ++j) {
            float re, im;
            Wq(Hu, tsg, q + 64 * s, w + 16 * j, re, im);
            acc[s][j] = (f32x2){re, im};
        }

    const int obq = q + (q >> 4);             // XI16(q); row q+64 -> obq+68

    float sgr = 1.0f, sgi = 0.0f;             // s = prod 2*a_k (wave 0 only)
    f32x2 cK0 = acc[0][0], cK1 = acc[1][0];   // extracted pivot col (j=K)

    for (int K = 0; K < 8; ++K) {
        // extract acc[*][K] -> cK (uniform 8-way ladder, once per 8 steps)
        cK0 = acc[0][0]; cK1 = acc[1][0];
#pragma unroll
        for (int j = 1; j < 8; ++j) {
            bool sel = (j == K);
            cK0 = sel ? acc[0][j] : cK0;
            cK1 = sel ? acc[1][j] : cK1;
        }
#pragma unroll
        for (int m = 0; m < 8; ++m) {
            const int k = (K << 3) + m;       // pair cols 2k=16K+2m, 2k+1
            if (k < 63) {
                const int par = m & 1;
                // stage: wave 2m stages col 2k (.xy), wave 2m+1 col 2k+1 (.zw)
                if (w == 2 * m) {
                    ((float2*)&xbuf[par][obq])[0]      = make_float2(cK0.x, cK0.y);
                    ((float2*)&xbuf[par][obq + 68])[0] = make_float2(cK1.x, cK1.y);
                } else if (w == 2 * m + 1) {
                    ((float2*)&xbuf[par][obq])[1]      = make_float2(cK0.x, cK0.y);
                    ((float2*)&xbuf[par][obq + 68])[1] = make_float2(cK1.x, cK1.y);
                }
                __syncthreads();
                // pivot a_k = W[2k][2k+1] (row 2k, c2 slot)
                float4 pv = xbuf[par][2 * k + (k >> 3)];    // XI16(2k)
                float arr = pv.z, aii = pv.w;
                float m2  = arr * arr + aii * aii;
                float den = __builtin_amdgcn_rcpf(m2);
                float ivr = arr * den, ivi = -aii * den;
                if (w == 0) {                 // sign chain only where consumed
                    float nsr = 2.0f * (sgr * arr - sgi * aii);
                    sgi = 2.0f * (sgr * aii + sgi * arr);
                    sgr = nsr;
                }
                // own-row staged values -> beta/gamma per stratum
                float4 own0 = xbuf[par][obq];
                float4 own1 = xbuf[par][obq + 68];
                float br0 = own0.z * ivr - own0.w * ivi;
                float bi0 = own0.z * ivi + own0.w * ivr;
                float gr0 = own0.x * ivr - own0.y * ivi;
                float gi0 = own0.x * ivi + own0.y * ivr;
                float br1 = own1.z * ivr - own1.w * ivi;
                float bi1 = own1.z * ivi + own1.w * ivr;
                float gr1 = own1.x * ivr - own1.y * ivi;
                float gi1 = own1.x * ivi + own1.y * ivr;
                const bool s0live = (k <= 30);
                // update register-held pivot col (col w+16K live iff w>=2m+2)
                if (w >= 2 * m + 2) {
                    float4 cv = xbuf[par][w + 17 * K];      // XI16(w+16K)
                    if (s0live) cK0 = upd8(cK0, br0, bi0, gr0, gi0, cv);
                    cK1 = upd8(cK1, br1, bi1, gr1, gi1, cv);
                }
                // update remaining live cols j>K (uniform guards, static idx)
#pragma unroll
                for (int j = 0; j < 8; ++j) {
                    if (j > K) {
                        float4 cv = xbuf[par][w + 17 * j];  // XI16(w+16j)
                        if (s0live) acc[0][j] = upd8(acc[0][j], br0, bi0, gr0, gi0, cv);
                        acc[1][j] = upd8(acc[1][j], br1, bi1, gr1, gi1, cv);
                    }
                }
            }
        }
    }

    __syncthreads();
    if (t == 1022)                            // w=15,q=62: row 126, col 127 = cK1
        xbuf[0][0] = make_float4(cK1.x, cK1.y, 0.0f, 0.0f);
    __syncthreads();
    if (t == 0) {
        float lr = xbuf[0][0].x, li = xbuf[0][0].y;      // a_63
        float snr = sgr * lr - sgi * li;       // s * a_63, |.| = 2^63 |Pf|
        float sni = sgr * li + sgi * lr;
        float mag = sqrtf(snr * snr + sni * sni);
        double sred = 0.0;
#pragma unroll
        for (int i = 0; i < 16; ++i) sred += red[i];
        double lt = -sred / 8.0;               // tr(H^2)/16 = -sum(v^2)/8
        double* lo = lows + (h * 128 + b) * 2;
        lo[0] = (double)logf(mag) + lt;        // = log|Pf| + 63 ln2 + lt
        lo[1] = atan2((double)sni, (double)snr) - PI_D;
    }
}

// --- combine: out(b) = Re logsumexp(lo1, log(s_prod)+lo2) as f32 -----------
extern "C" __global__ void gs_combine(const void* xin, const double* lows,
                                      float* out, int out_size) {
    int t = threadIdx.x;
    int mode = sniff_mode(xin);
    if (t < 128) {
        const double* lo1 = lows + t * 2;
        const double* lo2 = lows + (128 + t) * 2;
        double p = 1.0;
        for (int k = 0; k < 64; ++k) p *= ld_in(xin, t * 64 + k, mode);
        double a1r = lo1[0], a1i = lo1[1];
        double a2r = lo2[0], a2i = lo2[1] + (p < 0.0 ? PI_D : 0.0);
        double m = fmax(a1r, a2r);
        double s1, c1, s2, c2;
        sincos(a1i, &s1, &c1);
        sincos(a2i, &s2, &c2);
        double e1 = exp(a1r - m), e2 = exp(a2r - m);
        double zr = e1 * c1 + e2 * c2;
        double zi = e1 * s1 + e2 * s2;
        double outre = m + 0.5 * log(zr * zr + zi * zi);
        double outim = atan2(zi, zr);
        if (out_size >= 256) {                 // fallback: complex interleaved
            out[2 * t]     = (float)outre;
            out[2 * t + 1] = (float)outim;
        } else if (t < out_size) {             // primary: real part only (128)
            out[t] = (float)outre;
        }
    }
    for (int q = 256 + t; q < out_size; q += blockDim.x) out[q] = 0.0f;
}

extern "C" void kernel_launch(void* const* d_in, const int* in_sizes, int n_in,
                              void* d_out, int out_size, void* d_ws, size_t ws_size,
                              hipStream_t stream) {
    (void)ws_size;
    int xi = 0;
    for (int i = 0; i < n_in; ++i) if (in_sizes[i] == 8192) { xi = i; break; }
    const void* x = d_in[xi];
    const void* hh[2] = {nullptr, nullptr};
    int np = 0;
    for (int i = 0; i < n_in && np < 2; ++i) if (i != xi) hh[np++] = d_in[i];

    double* lows = (double*)d_ws;   // 512 doubles, fully rewritten every call

    GaussianState_24318104830346_kernel<<<256, 1024, 0, stream>>>(x, hh[0], hh[1], lows);
    gs_combine<<<1, 256, 0, stream>>>(x, lows, (float*)d_out, out_size);
}

// Round 20
// 76.023 us; speedup vs baseline: 1.1480x; 1.1480x over previous
//
#include <hip/hip_runtime.h>
#include <hip/hip_bf16.h>
#include <math.h>

// ---------------------------------------------------------------------------
// GaussianState: out(b) = Re logsumexp( lo(b,0), log(prod s)+lo(b,1) )
//   lo(b,h) = log Pf(W) + 63*ln2 - i*pi + lt(h);  lt = -sum(v^2)/8
// W: 128x128 complex skew, interleaved order; rank-2 Parlett-Reid, static 2x2
// pivots, deferred log (s = prod 2*a_k). Round 20 = round 18 (best, 75.9us)
// + (a) sign chain computed only on wave 0 (sole consumer is t==0),
// + (b) pivot read/reciprocal only when col-live -> dead waves skip the whole
//   step body except the barrier (round 19 showed per-step fixed work, not
//   balance, gates this regime).
// 1024 threads (4 waves/SIMD): wave w owns cols [8w,8w+8) (col-retirement
// wave-uniform, live iff k < 4w+3); rows q=t&63 + {0,64} (stratum 0 retires
// at k>30). acc[2][8] f32x2; ~64 VGPR, no spill.
// ---------------------------------------------------------------------------

#define PI_D  3.14159265358979323846264338328
#define LN2_D 0.69314718055994530941723212146

typedef float f32x2 __attribute__((ext_vector_type(2)));

__device__ __forceinline__ int sniff_mode(const void* x) {
    const unsigned int* u = (const unsigned int*)x;
    unsigned int lo = u[0], hi = u[1];
    if ((hi == 0x3FF00000u || hi == 0xBFF00000u) && lo == 0u) return 1;       // f64
    unsigned short a = (unsigned short)(lo & 0xFFFFu);
    unsigned short b = (unsigned short)(lo >> 16);
    if ((a == 0x3F80u || a == 0xBF80u) && (b == 0x3F80u || b == 0xBF80u)) return 2; // bf16
    return 0;                                                                  // f32
}

__device__ __forceinline__ double ld_in(const void* p, int idx, int mode) {
    if (mode == 1) return ((const double*)p)[idx];
    if (mode == 2) {
        unsigned int w = ((unsigned int)((const unsigned short*)p)[idx]) << 16;
        return (double)__uint_as_float(w);
    }
    return (double)((const float*)p)[idx];
}

// G(p,q) = -H[p][q]/2 from upper-tri storage of H (f32)
__device__ __forceinline__ float Gq(const float* Hu, int p, int q) {
    if (p == q) return 0.0f;
    int i = (p < q) ? p : q;
    int j = (p < q) ? q : p;
    float g = -0.5f * Hu[(i * (255 - i)) / 2 + (j - i - 1)];
    return (p < q) ? g : -g;
}

// W'(rn,cn) in interleaved order: even index -> old top q=n>>1, odd -> bottom.
__device__ __forceinline__ void Wq(const float* Hu, const float* tsg,
                                   int rn, int cn, float& re, float& im) {
    int A = rn >> 1, B = cn >> 1;
    if ((cn & 1) == 0) {
        if ((rn & 1) == 0) {
            re = 0.5f * (-Gq(Hu, 2*A, 2*B)   + Gq(Hu, 2*A+1, 2*B+1));
            im = 0.5f * (-Gq(Hu, 2*A, 2*B+1) - Gq(Hu, 2*A+1, 2*B));
        } else {
            int pA = (A + 1) & 63; float tA = tsg[A];
            float Fre = 0.5f * ( tA * Gq(Hu, 2*B, 2*A+1) + Gq(Hu, 2*B+1, 2*pA) );
            float Fim = 0.5f * ( -Gq(Hu, 2*B, 2*pA) + tA * Gq(Hu, 2*B+1, 2*A+1) );
            float Mim = 0.5f * ((B == A ? tA : 0.0f) - (B == pA ? 1.0f : 0.0f));
            re = Fre; im = Mim + Fim;
        }
    } else {
        if ((rn & 1) == 0) {
            int pB = (B + 1) & 63; float tB = tsg[B];
            float Fre = 0.5f * ( tB * Gq(Hu, 2*A, 2*B+1) + Gq(Hu, 2*A+1, 2*pB) );
            float Fim = 0.5f * ( -Gq(Hu, 2*A, 2*pB) + tB * Gq(Hu, 2*A+1, 2*B+1) );
            float Mim = 0.5f * ((A == B ? tB : 0.0f) - (A == pB ? 1.0f : 0.0f));
            re = -Fre; im = -Mim - Fim;
        } else {
            int pA = (A + 1) & 63, pB = (B + 1) & 63;
            float tA = tsg[A], tB = tsg[B];
            re = 0.5f * ( -tA * tB * Gq(Hu, 2*A+1, 2*B+1) + Gq(Hu, 2*pA, 2*pB) );
            im = 0.5f * (  tA * Gq(Hu, 2*A+1, 2*pB) + tB * Gq(Hu, 2*pA, 2*B+1) );
        }
    }
}

// --- per-(sample,ham) Pfaffian via 2x2-pivot block elimination -------------
// grid 256 = (b,h); 1024 threads: wave w=t>>6 -> cols [8w,8w+8),
// q=t&63 -> rows {q, q+64}.
extern "C" __global__ void __launch_bounds__(1024)
GaussianState_24318104830346_kernel(const void* xin, const void* h1,
                                    const void* h2, double* lows) {
    const int t   = threadIdx.x;
    const int bid = blockIdx.x;
    const int b = bid & 127, h = bid >> 7;
    const int w    = t >> 6;                  // wave id = col group (uniform)
    const int q    = t & 63;                  // row base
    const int lane = t & 63;

    __shared__ float  tsg[64];
    __shared__ float4 xbuf[2][136];           // XI16-padded staged col pairs
    __shared__ double red[16];
    __shared__ float  Hu[8128];

    const int mode = sniff_mode(xin);
    const void* raw = h ? h2 : h1;

    // stage upper-tri H + accumulate sum(v^2) for lt
    double ss = 0.0;
    for (int f = t; f < 8128; f += 1024) {
        double v = ld_in(raw, f, mode);
        Hu[f] = (float)v;
        ss += v * v;
    }
#pragma unroll
    for (int off = 32; off >= 1; off >>= 1) ss += __shfl_xor(ss, off, 64);
    if (lane == 0) red[w] = ss;

    if (t < 64) {
        float sA = (float)ld_in(xin, b * 64 + t, mode);
        float sB = (float)ld_in(xin, b * 64 + ((t + 1) & 63), mode);
        float tt = sA * sB;
        if (t == 63) tt = -tt;
        tsg[t] = tt;
    }
    __syncthreads();

    // build W' fragment: 2 strata x 8 cols, packed (re,im) in f32x2
    f32x2 acc[2][8];
#pragma unroll
    for (int s = 0; s < 2; ++s)
#pragma unroll
        for (int j = 0; j < 8; ++j) {
            float re, im;
            Wq(Hu, tsg, q + 64 * s, 8 * w + j, re, im);
            acc[s][j] = (f32x2){re, im};
        }

    const int cb  = 8 * w + (w >> 1);         // XI16 base of col range (uniform)
    const int obq = q + (q >> 4);             // XI16 idx of row q (+68 for q+64)

    float sgr = 1.0f, sgi = 0.0f;             // s = prod 2*a_k (wave 0 only)

    for (int K = 0; K < 16; ++K) {
#pragma unroll
        for (int m = 0; m < 4; ++m) {
            const int k = (K << 2) + m;
            if (k < 63) {
                const int par = m & 1;
                // stage pivot col pair 2k,2k+1 (owner wave; both strata)
                if (w == K) {
                    const int j2 = 2 * m;              // static
                    xbuf[par][obq] =
                        make_float4(acc[0][j2].x, acc[0][j2].y,
                                    acc[0][j2 + 1].x, acc[0][j2 + 1].y);
                    xbuf[par][obq + 68] =
                        make_float4(acc[1][j2].x, acc[1][j2].y,
                                    acc[1][j2 + 1].x, acc[1][j2 + 1].y);
                }
                __syncthreads();
                // sign chain: wave 0 only (sole consumer is t==0)
                if (w == 0) {
                    float4 pv = xbuf[par][2 * k + (k >> 3)];
                    float arr = pv.z, aii = pv.w;
                    float nsr = 2.0f * (sgr * arr - sgi * aii);
                    sgi = 2.0f * (sgr * aii + sgi * arr);
                    sgr = nsr;
                }
                if (k < 4 * w + 3) {                   // col-live (wave-uniform)
                    // pivot + reciprocal (live waves only)
                    float4 pv = xbuf[par][2 * k + (k >> 3)]; // XI16(2k)
                    float arr = pv.z, aii = pv.w;
                    float m2  = arr * arr + aii * aii;
                    float den = __builtin_amdgcn_rcpf(m2);
                    float ivr = arr * den, ivi = -aii * den;
                    // read the 8 column values ONCE (broadcast across lanes)
                    const float4* bp = &xbuf[par][cb];
                    f32x2 c1[8], c2[8];
#pragma unroll
                    for (int j = 0; j < 8; ++j) {
                        float4 cv = bp[j];
                        c1[j] = (f32x2){cv.x, cv.y};
                        c2[j] = (f32x2){cv.z, cv.w};
                    }
#pragma unroll
                    for (int s = 0; s < 2; ++s) {
                        if (s == 1 || k <= 30) {       // row-live (uniform)
                            float4 own = xbuf[par][obq + 68 * s];
                            float br = own.z * ivr - own.w * ivi;
                            float bi = own.z * ivi + own.w * ivr;
                            float gr = own.x * ivr - own.y * ivi;
                            float gi = own.x * ivi + own.y * ivr;
                            f32x2 bv  = (f32x2){ br,  br};
                            f32x2 bnv = (f32x2){-bi,  bi};
                            f32x2 gv  = (f32x2){-gr, -gr};
                            f32x2 gnv = (f32x2){ gi, -gi};
#pragma unroll
                            for (int j = 0; j < 8; ++j) {
                                f32x2 a = acc[s][j];
                                a = __builtin_elementwise_fma(bv,  c1[j],    a);
                                a = __builtin_elementwise_fma(bnv, c1[j].yx, a);
                                a = __builtin_elementwise_fma(gv,  c2[j],    a);
                                a = __builtin_elementwise_fma(gnv, c2[j].yx, a);
                                acc[s][j] = a;
                            }
                        }
                    }
                }
            }
        }
    }

    __syncthreads();
    if (t == 1022)                            // row 126 (q=62,s=1), col 127 (w=15,j=7)
        xbuf[0][0] = make_float4(acc[1][7].x, acc[1][7].y, 0.0f, 0.0f);
    __syncthreads();
    if (t == 0) {
        float lr = xbuf[0][0].x, li = xbuf[0][0].y;      // a_63
        float snr = sgr * lr - sgi * li;       // s * a_63, |.| = 2^63 |Pf|
        float sni = sgr * li + sgi * lr;
        float mag = sqrtf(snr * snr + sni * sni);
        double sred = 0.0;
#pragma unroll
        for (int i = 0; i < 16; ++i) sred += red[i];
        double lt = -sred / 8.0;               // tr(H^2)/16 = -sum(v^2)/8
        double* lo = lows + (h * 128 + b) * 2;
        lo[0] = (double)logf(mag) + lt;        // = log|Pf| + 63 ln2 + lt
        lo[1] = atan2((double)sni, (double)snr) - PI_D;
    }
}

// --- combine: out(b) = Re logsumexp(lo1, log(s_prod)+lo2) as f32 -----------
extern "C" __global__ void gs_combine(const void* xin, const double* lows,
                                      float* out, int out_size) {
    int t = threadIdx.x;
    int mode = sniff_mode(xin);
    if (t < 128) {
        const double* lo1 = lows + t * 2;
        const double* lo2 = lows + (128 + t) * 2;
        double p = 1.0;
        for (int k = 0; k < 64; ++k) p *= ld_in(xin, t * 64 + k, mode);
        double a1r = lo1[0], a1i = lo1[1];
        double a2r = lo2[0], a2i = lo2[1] + (p < 0.0 ? PI_D : 0.0);
        double m = fmax(a1r, a2r);
        double s1, c1, s2, c2;
        sincos(a1i, &s1, &c1);
        sincos(a2i, &s2, &c2);
        double e1 = exp(a1r - m), e2 = exp(a2r - m);
        double zr = e1 * c1 + e2 * c2;
        double zi = e1 * s1 + e2 * s2;
        double outre = m + 0.5 * log(zr * zr + zi * zi);
        double outim = atan2(zi, zr);
        if (out_size >= 256) {                 // fallback: complex interleaved
            out[2 * t]     = (float)outre;
            out[2 * t + 1] = (float)outim;
        } else if (t < out_size) {             // primary: real part only (128)
            out[t] = (float)outre;
        }
    }
    for (int q = 256 + t; q < out_size; q += blockDim.x) out[q] = 0.0f;
}

extern "C" void kernel_launch(void* const* d_in, const int* in_sizes, int n_in,
                              void* d_out, int out_size, void* d_ws, size_t ws_size,
                              hipStream_t stream) {
    (void)ws_size;
    int xi = 0;
    for (int i = 0; i < n_in; ++i) if (in_sizes[i] == 8192) { xi = i; break; }
    const void* x = d_in[xi];
    const void* hh[2] = {nullptr, nullptr};
    int np = 0;
    for (int i = 0; i < n_in && np < 2; ++i) if (i != xi) hh[np++] = d_in[i];

    double* lows = (double*)d_ws;   // 512 doubles, fully rewritten every call

    GaussianState_24318104830346_kernel<<<256, 1024, 0, stream>>>(x, hh[0], hh[1], lows);
    gs_combine<<<1, 256, 0, stream>>>(x, lows, (float*)d_out, out_size);
}